// Round 3
// baseline (2624.614 us; speedup 1.0000x reference)
//
#include <hip/hip_runtime.h>
#include <stdint.h>

#define N    4096
#define EMB  256
#define NH   4
#define HC   64     // channels per head
#define PAD  40     // LDS inner stride (elements): 80B = 20 banks -> <=2-way

typedef __attribute__((ext_vector_type(8))) short s16x8;   // 8 bf16 frag
typedef __attribute__((ext_vector_type(4))) float f32x4;
typedef __attribute__((ext_vector_type(4))) int   i32x4;
typedef unsigned short ushort_t;

__device__ __forceinline__ unsigned short f2bf(float f) {
  unsigned int u = __builtin_bit_cast(unsigned int, f);
  u += 0x7fffu + ((u >> 16) & 1u);      // RNE (finite values only)
  return (unsigned short)(u >> 16);
}

// ---------------- K0: W[k][m] -> WT[m][k] as bf16 (both weights, one launch)
__global__ void k_transpose_bf(const float* __restrict__ W0, ushort_t* __restrict__ WT0,
                               const float* __restrict__ W1, ushort_t* __restrict__ WT1) {
  int m = blockIdx.x & 255;
  int k = threadIdx.x;
  if (blockIdx.x < 256) WT0[m * EMB + k] = f2bf(W0[k * EMB + m]);
  else                  WT1[m * EMB + k] = f2bf(W1[k * EMB + m]);
}

// ---------------- K1: h = x @ W_lin (bf16 MFMA), epilogue:
//   hT[h][c][node] (bf16), a_srcT[h][node], a_dstT[h][node] (fp32) ----------
__global__ __launch_bounds__(256)
void k1_gemm_h(const float* __restrict__ x,
               const ushort_t* __restrict__ WlT,      // [256 m][256 k]
               const float* __restrict__ att_src,     // [4][64]
               const float* __restrict__ att_dst,
               ushort_t* __restrict__ hT,             // [4][64][4096]
               float* __restrict__ a_srcT,            // [4][4096]
               float* __restrict__ a_dstT)
{
  __shared__ ushort_t A_lds[64][PAD];
  __shared__ ushort_t B_lds[64][PAD];
  const int t = threadIdx.x;
  const int lane = t & 63;
  const int w = t >> 6;
  const int i0 = blockIdx.x * 64;
  const int head = blockIdx.y;
  const int c0 = head * 64;
  const int lq = lane >> 4, lm = lane & 15;
  const int srow = t >> 2, sko = (t & 3) * 8;

  f32x4 acc[4];
  #pragma unroll
  for (int nf = 0; nf < 4; ++nf) acc[nf] = f32x4{0.f, 0.f, 0.f, 0.f};

  for (int k0 = 0; k0 < EMB; k0 += 32) {
    __syncthreads();
    {
      const float* src = x + (i0 + srow) * EMB + k0 + sko;
      f32x4 v0 = *(const f32x4*)src;
      f32x4 v1 = *(const f32x4*)(src + 4);
      s16x8 p;
      p[0]=(short)f2bf(v0[0]); p[1]=(short)f2bf(v0[1]); p[2]=(short)f2bf(v0[2]); p[3]=(short)f2bf(v0[3]);
      p[4]=(short)f2bf(v1[0]); p[5]=(short)f2bf(v1[1]); p[6]=(short)f2bf(v1[2]); p[7]=(short)f2bf(v1[3]);
      *(s16x8*)&A_lds[srow][sko] = p;
      *(s16x8*)&B_lds[srow][sko] = *(const s16x8*)(WlT + (c0 + srow) * EMB + k0 + sko);
    }
    __syncthreads();
    s16x8 a = *(const s16x8*)&A_lds[w * 16 + lm][lq * 8];
    #pragma unroll
    for (int nf = 0; nf < 4; ++nf) {
      s16x8 b = *(const s16x8*)&B_lds[nf * 16 + lm][lq * 8];
      acc[nf] = __builtin_amdgcn_mfma_f32_16x16x32_bf16(a, b, acc[nf], 0, 0, 0);
    }
  }

  float ps[4] = {0.f,0.f,0.f,0.f}, pd[4] = {0.f,0.f,0.f,0.f};
  #pragma unroll
  for (int nf = 0; nf < 4; ++nf) {
    float wsv = att_src[c0 + nf * 16 + lm];
    float wdv = att_dst[c0 + nf * 16 + lm];
    #pragma unroll
    for (int r = 0; r < 4; ++r) {
      float v = acc[nf][r];
      int node = w * 16 + lq * 4 + r;                 // D: row=(lane>>4)*4+reg, col=lane&15
      hT[(c0 + nf * 16 + lm) * N + i0 + node] = f2bf(v);
      ps[r] += v * wsv;
      pd[r] += v * wdv;
    }
  }
  #pragma unroll
  for (int r = 0; r < 4; ++r) {
    #pragma unroll
    for (int mm = 1; mm < 16; mm <<= 1) {
      ps[r] += __shfl_xor(ps[r], mm);
      pd[r] += __shfl_xor(pd[r], mm);
    }
  }
  if (lm == 0) {
    #pragma unroll
    for (int r = 0; r < 4; ++r) {
      int node = i0 + w * 16 + lq * 4 + r;
      a_srcT[head * N + node] = ps[r];
      a_dstT[head * N + node] = pd[r];
    }
  }
}

// ---------------- K34: fused masked-softmax attention, atomic-free ---------
// Block = 512 thr = 8 waves = (4 heads x 2 j-halves); i-tile = 16 rows.
// Each wave: 16i x 64c for head h, sweeps 2048 j barrier-free with a 2-stage
// software pipeline. e computed directly in MFMA A-frag layout (trunc-bf16,
// denominator sums the same truncated values); h loaded directly as B-frag.
// j-halves reduced in LDS once; epilogue divides, adds bias, writes oat bf16.
// No global atomics, no split-K buffers, no separate normalize kernel.
__global__ __launch_bounds__(512)
void k34_attn(const int* __restrict__ adj,
              const ushort_t* __restrict__ hT,       // [4][64][4096]
              const float* __restrict__ a_srcT,      // [4][4096]
              const float* __restrict__ a_dstT,      // [4][4096]
              const float* __restrict__ bias_att,    // [256]
              ushort_t* __restrict__ oat)            // [4096][256]
{
  __shared__ float acc_lds[NH][16][65];   // jhalf=1 partial (pad 65: conflict-light)
  __shared__ float l_lds[NH][2][16];

  const int t = threadIdx.x;
  const int lane = t & 63;
  const int w = t >> 6;            // 0..7
  const int h = w & 3;             // head
  const int jh = w >> 2;           // j-half
  const int i0 = blockIdx.x * 16;
  const int lm = lane & 15, lq = lane >> 4;
  const int ig = i0 + lm;          // this lane's A-row (i)
  const int jbase = jh * (N / 2);

  const float* asrc_h = a_srcT + h * N;
  const ushort_t* hT_h = hT + h * HC * N;
  const float ad = a_dstT[h * N + ig];

  f32x4 acc[4];
  #pragma unroll
  for (int nf = 0; nf < 4; ++nf) acc[nf] = f32x4{0.f, 0.f, 0.f, 0.f};
  float lp = 0.f;

  // 2-stage software pipeline registers
  f32x4 as0[2], as1[2];
  i32x4 av0[2], av1[2];
  s16x8 bfr[2][4];

  auto stage_load = [&](int it, int s) {
    const int jl = jbase + it * 32 + lq * 8;
    as0[s] = *(const f32x4*)(asrc_h + jl);
    as1[s] = *(const f32x4*)(asrc_h + jl + 4);
    av0[s] = *(const i32x4*)(adj + (size_t)ig * N + jl);
    av1[s] = *(const i32x4*)(adj + (size_t)ig * N + jl + 4);
    #pragma unroll
    for (int nf = 0; nf < 4; ++nf)
      bfr[s][nf] = *(const s16x8*)(hT_h + (nf * 16 + lm) * N + jl);
  };

  stage_load(0, 0);
  for (int it = 0; it < (N / 2) / 32; ++it) {
    const int s = it & 1;
    if (it < (N / 2) / 32 - 1) stage_load(it + 1, s ^ 1);

    const int jl = jbase + it * 32 + lq * 8;
    unsigned int ebits[8];
    #pragma unroll
    for (int jj = 0; jj < 8; ++jj) {
      int avv   = (jj < 4) ? av0[s][jj] : av1[s][jj - 4];
      float asv = (jj < 4) ? as0[s][jj] : as1[s][jj - 4];
      float sc = asv + ad;
      sc = fmaxf(sc, 0.2f * sc);                   // leaky relu
      bool con = (avv != 0) || (jl + jj == ig);    // self-loop
      float e = con ? __expf(sc) : 0.f;
      unsigned int eb = __builtin_bit_cast(unsigned int, e) & 0xffff0000u; // trunc bf16
      ebits[jj] = eb;
      lp += __builtin_bit_cast(float, eb);         // sum the SAME rounded value
    }
    i32x4 pk;
    #pragma unroll
    for (int u = 0; u < 4; ++u)
      pk[u] = (int)__builtin_amdgcn_perm(ebits[2 * u + 1], ebits[2 * u], 0x07060302u);
    s16x8 af = __builtin_bit_cast(s16x8, pk);
    #pragma unroll
    for (int nf = 0; nf < 4; ++nf)
      acc[nf] = __builtin_amdgcn_mfma_f32_16x16x32_bf16(af, bfr[s][nf], acc[nf], 0, 0, 0);
  }

  // denominator: full half-row sum for row lm -> all lanes
  lp += __shfl_xor(lp, 16);
  lp += __shfl_xor(lp, 32);
  if (lq == 0) l_lds[h][jh][lm] = lp;

  // jhalf=1 parks its accumulator in LDS (C layout: row=lq*4+r, col=lm)
  if (jh == 1) {
    #pragma unroll
    for (int nf = 0; nf < 4; ++nf)
      #pragma unroll
      for (int r = 0; r < 4; ++r)
        acc_lds[h][lq * 4 + r][nf * 16 + lm] = acc[nf][r];
  }
  __syncthreads();
  if (jh == 0) {
    float linv[4];
    #pragma unroll
    for (int r = 0; r < 4; ++r)
      linv[r] = 1.f / (l_lds[h][0][lq * 4 + r] + l_lds[h][1][lq * 4 + r]);
    #pragma unroll
    for (int nf = 0; nf < 4; ++nf) {
      float bia = bias_att[h * 64 + nf * 16 + lm];
      #pragma unroll
      for (int r = 0; r < 4; ++r) {
        float v = acc[nf][r] + acc_lds[h][lq * 4 + r][nf * 16 + lm];
        oat[(size_t)(i0 + lq * 4 + r) * EMB + h * 64 + nf * 16 + lm] = f2bf(v * linv[r] + bia);
      }
    }
  }
}

// ---------------- K5: y = oat @ W_out + b_out, then LayerNorm -------------
__global__ __launch_bounds__(256)
void k5_gemm_ln(const ushort_t* __restrict__ oat,    // [4096][256]
                const ushort_t* __restrict__ WoT,    // [256 m][256 k]
                const float* __restrict__ b_out,
                const float* __restrict__ gamma,
                const float* __restrict__ beta,
                float* __restrict__ out)
{
  __shared__ ushort_t A_lds[32][PAD];
  __shared__ ushort_t B_lds[256][PAD];
  __shared__ float y_lds[32][260];
  const int t = threadIdx.x, lane = t & 63, w = t >> 6;
  const int i0 = blockIdx.x * 32;
  const int lq = lane >> 4, lm = lane & 15;

  f32x4 acc[2][4];
  #pragma unroll
  for (int a = 0; a < 2; ++a)
    #pragma unroll
    for (int b = 0; b < 4; ++b) acc[a][b] = f32x4{0.f, 0.f, 0.f, 0.f};

  for (int k0 = 0; k0 < EMB; k0 += 32) {
    __syncthreads();
    if (t < 128) {
      int row = t >> 2, ko = (t & 3) * 8;
      *(s16x8*)&A_lds[row][ko] = *(const s16x8*)(oat + (i0 + row) * EMB + k0 + ko);
    }
    {
      const ushort_t* src = WoT + t * EMB + k0;
      #pragma unroll
      for (int u = 0; u < 4; ++u) *(s16x8*)&B_lds[t][u * 8] = *(const s16x8*)(src + u * 8);
    }
    __syncthreads();
    s16x8 a0 = *(const s16x8*)&A_lds[lm][lq * 8];
    s16x8 a1 = *(const s16x8*)&A_lds[16 + lm][lq * 8];
    #pragma unroll
    for (int nf = 0; nf < 4; ++nf) {
      s16x8 b = *(const s16x8*)&B_lds[w * 64 + nf * 16 + lm][lq * 8];
      acc[0][nf] = __builtin_amdgcn_mfma_f32_16x16x32_bf16(a0, b, acc[0][nf], 0, 0, 0);
      acc[1][nf] = __builtin_amdgcn_mfma_f32_16x16x32_bf16(a1, b, acc[1][nf], 0, 0, 0);
    }
  }
  #pragma unroll
  for (int mf = 0; mf < 2; ++mf)
    #pragma unroll
    for (int nf = 0; nf < 4; ++nf)
      #pragma unroll
      for (int r = 0; r < 4; ++r) {
        int row = mf * 16 + lq * 4 + r;
        int col = w * 64 + nf * 16 + lm;
        y_lds[row][col] = acc[mf][nf][r] + b_out[col];
      }
  __syncthreads();
  f32x4 g  = *(const f32x4*)(gamma + lane * 4);
  f32x4 be = *(const f32x4*)(beta + lane * 4);
  for (int r = w * 8; r < w * 8 + 8; ++r) {
    f32x4 v = *(const f32x4*)&y_lds[r][lane * 4];
    float s1 = v[0] + v[1] + v[2] + v[3];
    float s2 = v[0]*v[0] + v[1]*v[1] + v[2]*v[2] + v[3]*v[3];
    #pragma unroll
    for (int mm = 1; mm < 64; mm <<= 1) { s1 += __shfl_xor(s1, mm); s2 += __shfl_xor(s2, mm); }
    float mu = s1 * (1.f / 256.f);
    float var = s2 * (1.f / 256.f) - mu * mu;
    float rs = rsqrtf(var + 1e-5f);
    f32x4 o;
    #pragma unroll
    for (int u = 0; u < 4; ++u) o[u] = (v[u] - mu) * rs * g[u] + be[u];
    *(f32x4*)(out + (i0 + r) * EMB + lane * 4) = o;
  }
}

extern "C" void kernel_launch(void* const* d_in, const int* in_sizes, int n_in,
                              void* d_out, int out_size, void* d_ws, size_t ws_size,
                              hipStream_t stream)
{
  (void)in_sizes; (void)n_in; (void)out_size; (void)ws_size;
  const float* x        = (const float*)d_in[0];
  const int*   adj      = (const int*)d_in[1];
  const float* W_lin    = (const float*)d_in[2];
  const float* att_src  = (const float*)d_in[3];
  const float* att_dst  = (const float*)d_in[4];
  const float* bias_att = (const float*)d_in[5];
  const float* W_out    = (const float*)d_in[6];
  const float* b_out    = (const float*)d_in[7];
  const float* gamma    = (const float*)d_in[8];
  const float* beta     = (const float*)d_in[9];
  float* out = (float*)d_out;

  uint8_t* p = (uint8_t*)d_ws;
  ushort_t* WlT = (ushort_t*)p;  p += (size_t)EMB * EMB * sizeof(ushort_t);
  ushort_t* WoT = (ushort_t*)p;  p += (size_t)EMB * EMB * sizeof(ushort_t);
  ushort_t* hT  = (ushort_t*)p;  p += (size_t)NH * HC * N * sizeof(ushort_t);
  float* a_srcb = (float*)p;     p += (size_t)NH * N * sizeof(float);
  float* a_dstb = (float*)p;     p += (size_t)NH * N * sizeof(float);
  ushort_t* oat = (ushort_t*)p;  p += (size_t)N * EMB * sizeof(ushort_t);

  k_transpose_bf<<<2 * EMB, EMB, 0, stream>>>(W_lin, WlT, W_out, WoT);
  k1_gemm_h<<<dim3(N / 64, NH), 256, 0, stream>>>(x, WlT, att_src, att_dst, hT, a_srcb, a_dstb);
  k34_attn<<<N / 16, 512, 0, stream>>>(adj, hT, a_srcb, a_dstb, bias_att, oat);
  k5_gemm_ln<<<N / 32, 256, 0, stream>>>(oat, WoT, b_out, gamma, beta, out);
}

// Round 4
// 220.907 us; speedup vs baseline: 11.8811x; 11.8811x over previous
//
#include <hip/hip_runtime.h>
#include <stdint.h>

#define N    4096
#define EMB  256
#define NH   4
#define HC   64     // channels per head
#define PAD  40     // LDS inner stride (elements): 80B = 20 banks -> <=2-way

typedef __attribute__((ext_vector_type(8))) short s16x8;   // 8 bf16 frag
typedef __attribute__((ext_vector_type(4))) float f32x4;
typedef __attribute__((ext_vector_type(4))) int   i32x4;
typedef unsigned short ushort_t;

__device__ __forceinline__ unsigned short f2bf(float f) {
  unsigned int u = __builtin_bit_cast(unsigned int, f);
  u += 0x7fffu + ((u >> 16) & 1u);      // RNE (finite values only)
  return (unsigned short)(u >> 16);
}

// ---------------- K0: W[k][m] -> WT[m][k] as bf16 (both weights, one launch)
__global__ void k_transpose_bf(const float* __restrict__ W0, ushort_t* __restrict__ WT0,
                               const float* __restrict__ W1, ushort_t* __restrict__ WT1) {
  int m = blockIdx.x & 255;
  int k = threadIdx.x;
  if (blockIdx.x < 256) WT0[m * EMB + k] = f2bf(W0[k * EMB + m]);
  else                  WT1[m * EMB + k] = f2bf(W1[k * EMB + m]);
}

// ---------------- K1: h = x @ W_lin (bf16 MFMA), epilogue:
//   hT[h][c][node] (bf16), a_srcT[h][node], a_dstT[h][node] (fp32) ----------
__global__ __launch_bounds__(256)
void k1_gemm_h(const float* __restrict__ x,
               const ushort_t* __restrict__ WlT,      // [256 m][256 k]
               const float* __restrict__ att_src,     // [4][64]
               const float* __restrict__ att_dst,
               ushort_t* __restrict__ hT,             // [4][64][4096]
               float* __restrict__ a_srcT,            // [4][4096]
               float* __restrict__ a_dstT)
{
  __shared__ ushort_t A_lds[64][PAD];
  __shared__ ushort_t B_lds[64][PAD];
  const int t = threadIdx.x;
  const int lane = t & 63;
  const int w = t >> 6;
  const int i0 = blockIdx.x * 64;
  const int head = blockIdx.y;
  const int c0 = head * 64;
  const int lq = lane >> 4, lm = lane & 15;
  const int srow = t >> 2, sko = (t & 3) * 8;

  f32x4 acc[4];
  #pragma unroll
  for (int nf = 0; nf < 4; ++nf) acc[nf] = f32x4{0.f, 0.f, 0.f, 0.f};

  for (int k0 = 0; k0 < EMB; k0 += 32) {
    __syncthreads();
    {
      const float* src = x + (i0 + srow) * EMB + k0 + sko;
      f32x4 v0 = *(const f32x4*)src;
      f32x4 v1 = *(const f32x4*)(src + 4);
      s16x8 p;
      p[0]=(short)f2bf(v0[0]); p[1]=(short)f2bf(v0[1]); p[2]=(short)f2bf(v0[2]); p[3]=(short)f2bf(v0[3]);
      p[4]=(short)f2bf(v1[0]); p[5]=(short)f2bf(v1[1]); p[6]=(short)f2bf(v1[2]); p[7]=(short)f2bf(v1[3]);
      *(s16x8*)&A_lds[srow][sko] = p;
      *(s16x8*)&B_lds[srow][sko] = *(const s16x8*)(WlT + (c0 + srow) * EMB + k0 + sko);
    }
    __syncthreads();
    s16x8 a = *(const s16x8*)&A_lds[w * 16 + lm][lq * 8];
    #pragma unroll
    for (int nf = 0; nf < 4; ++nf) {
      s16x8 b = *(const s16x8*)&B_lds[nf * 16 + lm][lq * 8];
      acc[nf] = __builtin_amdgcn_mfma_f32_16x16x32_bf16(a, b, acc[nf], 0, 0, 0);
    }
  }

  float ps[4] = {0.f,0.f,0.f,0.f}, pd[4] = {0.f,0.f,0.f,0.f};
  #pragma unroll
  for (int nf = 0; nf < 4; ++nf) {
    float wsv = att_src[c0 + nf * 16 + lm];
    float wdv = att_dst[c0 + nf * 16 + lm];
    #pragma unroll
    for (int r = 0; r < 4; ++r) {
      float v = acc[nf][r];
      int node = w * 16 + lq * 4 + r;                 // D: row=(lane>>4)*4+reg, col=lane&15
      hT[(c0 + nf * 16 + lm) * N + i0 + node] = f2bf(v);
      ps[r] += v * wsv;
      pd[r] += v * wdv;
    }
  }
  #pragma unroll
  for (int r = 0; r < 4; ++r) {
    #pragma unroll
    for (int mm = 1; mm < 16; mm <<= 1) {
      ps[r] += __shfl_xor(ps[r], mm);
      pd[r] += __shfl_xor(pd[r], mm);
    }
  }
  if (lm == 0) {
    #pragma unroll
    for (int r = 0; r < 4; ++r) {
      int node = i0 + w * 16 + lq * 4 + r;
      a_srcT[head * N + node] = ps[r];
      a_dstT[head * N + node] = pd[r];
    }
  }
}

// ---------------- K34: fused masked-softmax attention, atomic-free ---------
// Block = 1024 thr = 16 waves = (4 heads x 4 j-quarters); i-tile = 16 rows.
// Each wave: 16i x 64c for head h, sweeps 1024 j barrier-free. e computed
// directly in MFMA A-frag layout (trunc-bf16; denominator sums the same
// truncated values); h loaded directly as B-frag. NO runtime-indexed local
// arrays (round-3 scratch-spill lesson: VGPR=84 + scratch = 16x slowdown).
// j-quarters reduced in LDS once; epilogue divides, adds bias, writes oat.
__global__ __launch_bounds__(1024, 4)
void k34_attn(const int* __restrict__ adj,
              const ushort_t* __restrict__ hT,       // [4][64][4096]
              const float* __restrict__ a_srcT,      // [4][4096]
              const float* __restrict__ a_dstT,      // [4][4096]
              const float* __restrict__ bias_att,    // [256]
              ushort_t* __restrict__ oat)            // [4096][256]
{
  __shared__ float acc_lds[NH][3][16][65];  // jq=1..3 partials (pad 65)
  __shared__ float l_lds[NH][4][16];

  const int t = threadIdx.x;
  const int lane = t & 63;
  const int w = t >> 6;            // 0..15
  const int h = w & 3;             // head
  const int jq = w >> 2;           // j-quarter 0..3
  const int i0 = blockIdx.x * 16;
  const int lm = lane & 15, lq = lane >> 4;
  const int ig = i0 + lm;          // this lane's A-row (i)
  const int jbase = jq * (N / 4);

  const float* asrc_h = a_srcT + h * N;
  const ushort_t* hT_h = hT + h * HC * N;
  const float ad = a_dstT[h * N + ig];

  f32x4 acc[4];
  #pragma unroll
  for (int nf = 0; nf < 4; ++nf) acc[nf] = f32x4{0.f, 0.f, 0.f, 0.f};
  float lp = 0.f;

  const int* adj_row = adj + (size_t)ig * N;

  #pragma unroll 2
  for (int it = 0; it < (N / 4) / 32; ++it) {
    const int jl = jbase + it * 32 + lq * 8;

    f32x4 as0 = *(const f32x4*)(asrc_h + jl);
    f32x4 as1 = *(const f32x4*)(asrc_h + jl + 4);
    i32x4 av0 = *(const i32x4*)(adj_row + jl);
    i32x4 av1 = *(const i32x4*)(adj_row + jl + 4);
    s16x8 b0 = *(const s16x8*)(hT_h + (0 * 16 + lm) * N + jl);
    s16x8 b1 = *(const s16x8*)(hT_h + (1 * 16 + lm) * N + jl);
    s16x8 b2 = *(const s16x8*)(hT_h + (2 * 16 + lm) * N + jl);
    s16x8 b3 = *(const s16x8*)(hT_h + (3 * 16 + lm) * N + jl);

    unsigned int ebits[8];
    #pragma unroll
    for (int jj = 0; jj < 8; ++jj) {
      int avv   = (jj < 4) ? av0[jj] : av1[jj - 4];
      float asv = (jj < 4) ? as0[jj] : as1[jj - 4];
      float sc = asv + ad;
      sc = fmaxf(sc, 0.2f * sc);                   // leaky relu
      bool con = (avv != 0) || (jl + jj == ig);    // self-loop
      float e = con ? __expf(sc) : 0.f;
      unsigned int eb = __builtin_bit_cast(unsigned int, e) & 0xffff0000u; // trunc bf16
      ebits[jj] = eb;
      lp += __builtin_bit_cast(float, eb);         // sum the SAME rounded value
    }
    i32x4 pk;
    #pragma unroll
    for (int u = 0; u < 4; ++u)
      pk[u] = (int)__builtin_amdgcn_perm(ebits[2 * u + 1], ebits[2 * u], 0x07060302u);
    s16x8 af = __builtin_bit_cast(s16x8, pk);

    acc[0] = __builtin_amdgcn_mfma_f32_16x16x32_bf16(af, b0, acc[0], 0, 0, 0);
    acc[1] = __builtin_amdgcn_mfma_f32_16x16x32_bf16(af, b1, acc[1], 0, 0, 0);
    acc[2] = __builtin_amdgcn_mfma_f32_16x16x32_bf16(af, b2, acc[2], 0, 0, 0);
    acc[3] = __builtin_amdgcn_mfma_f32_16x16x32_bf16(af, b3, acc[3], 0, 0, 0);
  }

  // denominator: full quarter-row sum for row lm -> lanes with lq==0 store
  lp += __shfl_xor(lp, 16);
  lp += __shfl_xor(lp, 32);
  if (lq == 0) l_lds[h][jq][lm] = lp;

  // jq=1..3 park accumulators in LDS (C layout: row=lq*4+r, col=lm)
  if (jq != 0) {
    #pragma unroll
    for (int nf = 0; nf < 4; ++nf)
      #pragma unroll
      for (int r = 0; r < 4; ++r)
        acc_lds[h][jq - 1][lq * 4 + r][nf * 16 + lm] = acc[nf][r];
  }
  __syncthreads();
  if (jq == 0) {
    float linv[4];
    #pragma unroll
    for (int r = 0; r < 4; ++r) {
      int row = lq * 4 + r;
      linv[r] = 1.f / (l_lds[h][0][row] + l_lds[h][1][row] +
                       l_lds[h][2][row] + l_lds[h][3][row]);
    }
    #pragma unroll
    for (int nf = 0; nf < 4; ++nf) {
      float bia = bias_att[h * 64 + nf * 16 + lm];
      #pragma unroll
      for (int r = 0; r < 4; ++r) {
        int row = lq * 4 + r;
        float v = acc[nf][r] + acc_lds[h][0][row][nf * 16 + lm]
                             + acc_lds[h][1][row][nf * 16 + lm]
                             + acc_lds[h][2][row][nf * 16 + lm];
        oat[(size_t)(i0 + row) * EMB + h * 64 + nf * 16 + lm] = f2bf(v * linv[r] + bia);
      }
    }
  }
}

// ---------------- K5: y = oat @ W_out + b_out, then LayerNorm -------------
__global__ __launch_bounds__(256)
void k5_gemm_ln(const ushort_t* __restrict__ oat,    // [4096][256]
                const ushort_t* __restrict__ WoT,    // [256 m][256 k]
                const float* __restrict__ b_out,
                const float* __restrict__ gamma,
                const float* __restrict__ beta,
                float* __restrict__ out)
{
  __shared__ ushort_t A_lds[32][PAD];
  __shared__ ushort_t B_lds[256][PAD];
  __shared__ float y_lds[32][260];
  const int t = threadIdx.x, lane = t & 63, w = t >> 6;
  const int i0 = blockIdx.x * 32;
  const int lq = lane >> 4, lm = lane & 15;

  f32x4 acc[2][4];
  #pragma unroll
  for (int a = 0; a < 2; ++a)
    #pragma unroll
    for (int b = 0; b < 4; ++b) acc[a][b] = f32x4{0.f, 0.f, 0.f, 0.f};

  for (int k0 = 0; k0 < EMB; k0 += 32) {
    __syncthreads();
    if (t < 128) {
      int row = t >> 2, ko = (t & 3) * 8;
      *(s16x8*)&A_lds[row][ko] = *(const s16x8*)(oat + (i0 + row) * EMB + k0 + ko);
    }
    {
      const ushort_t* src = WoT + t * EMB + k0;
      #pragma unroll
      for (int u = 0; u < 4; ++u) *(s16x8*)&B_lds[t][u * 8] = *(const s16x8*)(src + u * 8);
    }
    __syncthreads();
    s16x8 a0 = *(const s16x8*)&A_lds[lm][lq * 8];
    s16x8 a1 = *(const s16x8*)&A_lds[16 + lm][lq * 8];
    #pragma unroll
    for (int nf = 0; nf < 4; ++nf) {
      s16x8 b = *(const s16x8*)&B_lds[w * 64 + nf * 16 + lm][lq * 8];
      acc[0][nf] = __builtin_amdgcn_mfma_f32_16x16x32_bf16(a0, b, acc[0][nf], 0, 0, 0);
      acc[1][nf] = __builtin_amdgcn_mfma_f32_16x16x32_bf16(a1, b, acc[1][nf], 0, 0, 0);
    }
  }
  #pragma unroll
  for (int mf = 0; mf < 2; ++mf)
    #pragma unroll
    for (int nf = 0; nf < 4; ++nf)
      #pragma unroll
      for (int r = 0; r < 4; ++r) {
        int row = mf * 16 + lq * 4 + r;
        int col = w * 64 + nf * 16 + lm;
        y_lds[row][col] = acc[mf][nf][r] + b_out[col];
      }
  __syncthreads();
  f32x4 g  = *(const f32x4*)(gamma + lane * 4);
  f32x4 be = *(const f32x4*)(beta + lane * 4);
  for (int r = w * 8; r < w * 8 + 8; ++r) {
    f32x4 v = *(const f32x4*)&y_lds[r][lane * 4];
    float s1 = v[0] + v[1] + v[2] + v[3];
    float s2 = v[0]*v[0] + v[1]*v[1] + v[2]*v[2] + v[3]*v[3];
    #pragma unroll
    for (int mm = 1; mm < 64; mm <<= 1) { s1 += __shfl_xor(s1, mm); s2 += __shfl_xor(s2, mm); }
    float mu = s1 * (1.f / 256.f);
    float var = s2 * (1.f / 256.f) - mu * mu;
    float rs = rsqrtf(var + 1e-5f);
    f32x4 o;
    #pragma unroll
    for (int u = 0; u < 4; ++u) o[u] = (v[u] - mu) * rs * g[u] + be[u];
    *(f32x4*)(out + (i0 + r) * EMB + lane * 4) = o;
  }
}

extern "C" void kernel_launch(void* const* d_in, const int* in_sizes, int n_in,
                              void* d_out, int out_size, void* d_ws, size_t ws_size,
                              hipStream_t stream)
{
  (void)in_sizes; (void)n_in; (void)out_size; (void)ws_size;
  const float* x        = (const float*)d_in[0];
  const int*   adj      = (const int*)d_in[1];
  const float* W_lin    = (const float*)d_in[2];
  const float* att_src  = (const float*)d_in[3];
  const float* att_dst  = (const float*)d_in[4];
  const float* bias_att = (const float*)d_in[5];
  const float* W_out    = (const float*)d_in[6];
  const float* b_out    = (const float*)d_in[7];
  const float* gamma    = (const float*)d_in[8];
  const float* beta     = (const float*)d_in[9];
  float* out = (float*)d_out;

  uint8_t* p = (uint8_t*)d_ws;
  ushort_t* WlT = (ushort_t*)p;  p += (size_t)EMB * EMB * sizeof(ushort_t);
  ushort_t* WoT = (ushort_t*)p;  p += (size_t)EMB * EMB * sizeof(ushort_t);
  ushort_t* hT  = (ushort_t*)p;  p += (size_t)NH * HC * N * sizeof(ushort_t);
  float* a_srcb = (float*)p;     p += (size_t)NH * N * sizeof(float);
  float* a_dstb = (float*)p;     p += (size_t)NH * N * sizeof(float);
  ushort_t* oat = (ushort_t*)p;  p += (size_t)N * EMB * sizeof(ushort_t);

  k_transpose_bf<<<2 * EMB, EMB, 0, stream>>>(W_lin, WlT, W_out, WoT);
  k1_gemm_h<<<dim3(N / 64, NH), 256, 0, stream>>>(x, WlT, att_src, att_dst, hT, a_srcb, a_dstb);
  k34_attn<<<N / 16, 1024, 0, stream>>>(adj, hT, a_srcb, a_dstb, bias_att, oat);
  k5_gemm_ln<<<N / 32, 256, 0, stream>>>(oat, WoT, b_out, gamma, beta, out);
}

// Round 5
// 218.040 us; speedup vs baseline: 12.0373x; 1.0131x over previous
//
#include <hip/hip_runtime.h>
#include <stdint.h>

#define N    4096
#define EMB  256
#define NH   4
#define HC   64     // channels per head
#define PAD  40     // LDS inner stride (elements): 80B = 20 banks -> <=2-way

typedef __attribute__((ext_vector_type(8))) short s16x8;   // 8 bf16 frag
typedef __attribute__((ext_vector_type(4))) float f32x4;
typedef __attribute__((ext_vector_type(4))) int   i32x4;
typedef unsigned short ushort_t;

__device__ __forceinline__ unsigned short f2bf(float f) {
  unsigned int u = __builtin_bit_cast(unsigned int, f);
  u += 0x7fffu + ((u >> 16) & 1u);      // RNE (finite values only)
  return (unsigned short)(u >> 16);
}

// ---------------- K0: W[k][m] -> WT[m][k] as bf16 (both weights, one launch)
// Coalesced READ (lanes sweep m), scattered write (stores don't stall).
__global__ void k_transpose_bf(const float* __restrict__ W0, ushort_t* __restrict__ WT0,
                               const float* __restrict__ W1, ushort_t* __restrict__ WT1) {
  int k = blockIdx.x & 255;
  int m = threadIdx.x;
  if (blockIdx.x < 256) WT0[m * EMB + k] = f2bf(W0[k * EMB + m]);
  else                  WT1[m * EMB + k] = f2bf(W1[k * EMB + m]);
}

// ---------------- K1: h = x @ W_lin (bf16 MFMA), epilogue:
//   hT[h][c][node] (bf16, LDS-repacked coalesced store),
//   a_srcT[h][node], a_dstT[h][node] (fp32) ----------
__global__ __launch_bounds__(256, 2)
void k1_gemm_h(const float* __restrict__ x,
               const ushort_t* __restrict__ WlT,      // [256 m][256 k]
               const float* __restrict__ att_src,     // [4][64]
               const float* __restrict__ att_dst,
               ushort_t* __restrict__ hT,             // [4][64][4096]
               float* __restrict__ a_srcT,            // [4][4096]
               float* __restrict__ a_dstT)
{
  __shared__ ushort_t A_lds[64][PAD];
  __shared__ ushort_t B_lds[64][PAD];
  __shared__ ushort_t T_lds[64][72];    // repack tile [c][node], 72: 16B-aligned rows
  const int t = threadIdx.x;
  const int lane = t & 63;
  const int w = t >> 6;
  const int i0 = blockIdx.x * 64;
  const int head = blockIdx.y;
  const int c0 = head * 64;
  const int lq = lane >> 4, lm = lane & 15;
  const int srow = t >> 2, sko = (t & 3) * 8;

  f32x4 acc[4];
  #pragma unroll
  for (int nf = 0; nf < 4; ++nf) acc[nf] = f32x4{0.f, 0.f, 0.f, 0.f};

  for (int k0 = 0; k0 < EMB; k0 += 32) {
    __syncthreads();
    {
      const float* src = x + (i0 + srow) * EMB + k0 + sko;
      f32x4 v0 = *(const f32x4*)src;
      f32x4 v1 = *(const f32x4*)(src + 4);
      s16x8 p;
      p[0]=(short)f2bf(v0[0]); p[1]=(short)f2bf(v0[1]); p[2]=(short)f2bf(v0[2]); p[3]=(short)f2bf(v0[3]);
      p[4]=(short)f2bf(v1[0]); p[5]=(short)f2bf(v1[1]); p[6]=(short)f2bf(v1[2]); p[7]=(short)f2bf(v1[3]);
      *(s16x8*)&A_lds[srow][sko] = p;
      *(s16x8*)&B_lds[srow][sko] = *(const s16x8*)(WlT + (c0 + srow) * EMB + k0 + sko);
    }
    __syncthreads();
    s16x8 a = *(const s16x8*)&A_lds[w * 16 + lm][lq * 8];
    #pragma unroll
    for (int nf = 0; nf < 4; ++nf) {
      s16x8 b = *(const s16x8*)&B_lds[nf * 16 + lm][lq * 8];
      acc[nf] = __builtin_amdgcn_mfma_f32_16x16x32_bf16(a, b, acc[nf], 0, 0, 0);
    }
  }

  float ps[4] = {0.f,0.f,0.f,0.f}, pd[4] = {0.f,0.f,0.f,0.f};
  #pragma unroll
  for (int nf = 0; nf < 4; ++nf) {
    float wsv = att_src[c0 + nf * 16 + lm];
    float wdv = att_dst[c0 + nf * 16 + lm];
    #pragma unroll
    for (int r = 0; r < 4; ++r) {
      float v = acc[nf][r];
      int node = w * 16 + lq * 4 + r;                 // D: row=(lane>>4)*4+reg, col=lane&15
      T_lds[nf * 16 + lm][node] = f2bf(v);            // park C^T tile in LDS
      ps[r] += v * wsv;
      pd[r] += v * wdv;
    }
  }
  #pragma unroll
  for (int r = 0; r < 4; ++r) {
    #pragma unroll
    for (int mm = 1; mm < 16; mm <<= 1) {
      ps[r] += __shfl_xor(ps[r], mm);
      pd[r] += __shfl_xor(pd[r], mm);
    }
  }
  if (lm == 0) {
    #pragma unroll
    for (int r = 0; r < 4; ++r) {
      int node = i0 + w * 16 + lq * 4 + r;
      a_srcT[head * N + node] = ps[r];
      a_dstT[head * N + node] = pd[r];
    }
  }
  __syncthreads();
  // coalesced hT store: thread t -> row c=t>>2, 32B segment seg=t&3
  {
    int c = t >> 2, seg = t & 3;
    s16x8 v0 = *(const s16x8*)&T_lds[c][seg * 16];
    s16x8 v1 = *(const s16x8*)&T_lds[c][seg * 16 + 8];
    ushort_t* dst = hT + (size_t)(c0 + c) * N + i0 + seg * 16;
    *(s16x8*)dst = v0;
    *(s16x8*)(dst + 8) = v1;
  }
}

// ---------------- K34: fused masked-softmax attention, atomic-free ---------
// Block = 512 thr = 8 waves = (2 heads x 4 j-quarters); i-tile = 16 rows;
// grid = (N/16, 2 head-pairs) = 512 blocks -> 2 blocks/CU, 16 waves/CU.
// NOTE __launch_bounds__ 2nd arg behaves as CUDA min-BLOCKS/CU here
// (R4 evidence: (1024,4) -> VGPR=32=512/16): (512,2) -> 4 waves/EU -> cap 128.
// e computed directly in MFMA A-frag layout (trunc-bf16; denominator sums the
// same truncated values); h loaded directly as B-frag. Static indexing only.
__global__ __launch_bounds__(512, 2)
void k34_attn(const int* __restrict__ adj,
              const ushort_t* __restrict__ hT,       // [4][64][4096]
              const float* __restrict__ a_srcT,      // [4][4096]
              const float* __restrict__ a_dstT,      // [4][4096]
              const float* __restrict__ bias_att,    // [256]
              ushort_t* __restrict__ oat)            // [4096][256]
{
  __shared__ float acc_lds[2][3][16][65];  // jq=1..3 partials per local head
  __shared__ float l_lds[2][4][16];

  const int t = threadIdx.x;
  const int lane = t & 63;
  const int w = t >> 6;            // 0..7
  const int hloc = w & 1;          // local head (of the pair)
  const int jq = w >> 1;           // j-quarter 0..3
  const int head = blockIdx.y * 2 + hloc;
  const int i0 = blockIdx.x * 16;
  const int lm = lane & 15, lq = lane >> 4;
  const int ig = i0 + lm;          // this lane's A-row (i)
  const int jbase = jq * (N / 4);

  const float* asrc_h = a_srcT + head * N;
  const ushort_t* hT_h = hT + (size_t)head * HC * N;
  const float ad = a_dstT[head * N + ig];

  f32x4 acc[4];
  #pragma unroll
  for (int nf = 0; nf < 4; ++nf) acc[nf] = f32x4{0.f, 0.f, 0.f, 0.f};
  float lp = 0.f;

  const int* adj_row = adj + (size_t)ig * N;

  #pragma unroll 2
  for (int it = 0; it < (N / 4) / 32; ++it) {
    const int jl = jbase + it * 32 + lq * 8;

    f32x4 as0 = *(const f32x4*)(asrc_h + jl);
    f32x4 as1 = *(const f32x4*)(asrc_h + jl + 4);
    i32x4 av0 = *(const i32x4*)(adj_row + jl);
    i32x4 av1 = *(const i32x4*)(adj_row + jl + 4);
    s16x8 b0 = *(const s16x8*)(hT_h + (0 * 16 + lm) * N + jl);
    s16x8 b1 = *(const s16x8*)(hT_h + (1 * 16 + lm) * N + jl);
    s16x8 b2 = *(const s16x8*)(hT_h + (2 * 16 + lm) * N + jl);
    s16x8 b3 = *(const s16x8*)(hT_h + (3 * 16 + lm) * N + jl);

    unsigned int ebits[8];
    #pragma unroll
    for (int jj = 0; jj < 8; ++jj) {
      int avv   = (jj < 4) ? av0[jj] : av1[jj - 4];
      float asv = (jj < 4) ? as0[jj] : as1[jj - 4];
      float sc = asv + ad;
      sc = fmaxf(sc, 0.2f * sc);                   // leaky relu
      bool con = (avv != 0) || (jl + jj == ig);    // self-loop
      float e = con ? __expf(sc) : 0.f;
      unsigned int eb = __builtin_bit_cast(unsigned int, e) & 0xffff0000u; // trunc bf16
      ebits[jj] = eb;
      lp += __builtin_bit_cast(float, eb);         // sum the SAME rounded value
    }
    i32x4 pk;
    #pragma unroll
    for (int u = 0; u < 4; ++u)
      pk[u] = (int)__builtin_amdgcn_perm(ebits[2 * u + 1], ebits[2 * u], 0x07060302u);
    s16x8 af = __builtin_bit_cast(s16x8, pk);

    acc[0] = __builtin_amdgcn_mfma_f32_16x16x32_bf16(af, b0, acc[0], 0, 0, 0);
    acc[1] = __builtin_amdgcn_mfma_f32_16x16x32_bf16(af, b1, acc[1], 0, 0, 0);
    acc[2] = __builtin_amdgcn_mfma_f32_16x16x32_bf16(af, b2, acc[2], 0, 0, 0);
    acc[3] = __builtin_amdgcn_mfma_f32_16x16x32_bf16(af, b3, acc[3], 0, 0, 0);
  }

  // denominator: quarter-row sum for row lm
  lp += __shfl_xor(lp, 16);
  lp += __shfl_xor(lp, 32);
  if (lq == 0) l_lds[hloc][jq][lm] = lp;

  // jq=1..3 park accumulators in LDS (C layout: row=lq*4+r, col=lm)
  if (jq != 0) {
    #pragma unroll
    for (int nf = 0; nf < 4; ++nf)
      #pragma unroll
      for (int r = 0; r < 4; ++r)
        acc_lds[hloc][jq - 1][lq * 4 + r][nf * 16 + lm] = acc[nf][r];
  }
  __syncthreads();
  if (jq == 0) {
    float linv[4];
    #pragma unroll
    for (int r = 0; r < 4; ++r) {
      int row = lq * 4 + r;
      linv[r] = 1.f / (l_lds[hloc][0][row] + l_lds[hloc][1][row] +
                       l_lds[hloc][2][row] + l_lds[hloc][3][row]);
    }
    #pragma unroll
    for (int nf = 0; nf < 4; ++nf) {
      float bia = bias_att[head * 64 + nf * 16 + lm];
      #pragma unroll
      for (int r = 0; r < 4; ++r) {
        int row = lq * 4 + r;
        float v = acc[nf][r] + acc_lds[hloc][0][row][nf * 16 + lm]
                             + acc_lds[hloc][1][row][nf * 16 + lm]
                             + acc_lds[hloc][2][row][nf * 16 + lm];
        oat[(size_t)(i0 + row) * EMB + head * 64 + nf * 16 + lm] = f2bf(v * linv[r] + bia);
      }
    }
  }
}

// ---------------- K5: y = oat @ W_out + b_out, then LayerNorm -------------
// i-tile 16 -> grid 256 (was 128: half the CUs idle).
__global__ __launch_bounds__(256, 2)
void k5_gemm_ln(const ushort_t* __restrict__ oat,    // [4096][256]
                const ushort_t* __restrict__ WoT,    // [256 m][256 k]
                const float* __restrict__ b_out,
                const float* __restrict__ gamma,
                const float* __restrict__ beta,
                float* __restrict__ out)
{
  __shared__ ushort_t A_lds[16][PAD];
  __shared__ ushort_t B_lds[256][PAD];
  __shared__ float y_lds[16][260];
  const int t = threadIdx.x, lane = t & 63, w = t >> 6;
  const int i0 = blockIdx.x * 16;
  const int lq = lane >> 4, lm = lane & 15;

  f32x4 acc[4];
  #pragma unroll
  for (int nf = 0; nf < 4; ++nf) acc[nf] = f32x4{0.f, 0.f, 0.f, 0.f};

  for (int k0 = 0; k0 < EMB; k0 += 32) {
    __syncthreads();
    if (t < 64) {
      int row = t >> 2, ko = (t & 3) * 8;
      *(s16x8*)&A_lds[row][ko] = *(const s16x8*)(oat + (size_t)(i0 + row) * EMB + k0 + ko);
    }
    {
      const ushort_t* src = WoT + t * EMB + k0;
      #pragma unroll
      for (int u = 0; u < 4; ++u) *(s16x8*)&B_lds[t][u * 8] = *(const s16x8*)(src + u * 8);
    }
    __syncthreads();
    s16x8 a = *(const s16x8*)&A_lds[lm][lq * 8];
    #pragma unroll
    for (int nf = 0; nf < 4; ++nf) {
      s16x8 b = *(const s16x8*)&B_lds[w * 64 + nf * 16 + lm][lq * 8];
      acc[nf] = __builtin_amdgcn_mfma_f32_16x16x32_bf16(a, b, acc[nf], 0, 0, 0);
    }
  }
  #pragma unroll
  for (int nf = 0; nf < 4; ++nf)
    #pragma unroll
    for (int r = 0; r < 4; ++r) {
      int row = lq * 4 + r;
      int col = w * 64 + nf * 16 + lm;
      y_lds[row][col] = acc[nf][r] + b_out[col];
    }
  __syncthreads();
  f32x4 g  = *(const f32x4*)(gamma + lane * 4);
  f32x4 be = *(const f32x4*)(beta + lane * 4);
  #pragma unroll
  for (int r = w * 4; r < w * 4 + 4; ++r) {
    f32x4 v = *(const f32x4*)&y_lds[r][lane * 4];
    float s1 = v[0] + v[1] + v[2] + v[3];
    float s2 = v[0]*v[0] + v[1]*v[1] + v[2]*v[2] + v[3]*v[3];
    #pragma unroll
    for (int mm = 1; mm < 64; mm <<= 1) { s1 += __shfl_xor(s1, mm); s2 += __shfl_xor(s2, mm); }
    float mu = s1 * (1.f / 256.f);
    float var = s2 * (1.f / 256.f) - mu * mu;
    float rs = rsqrtf(var + 1e-5f);
    f32x4 o;
    #pragma unroll
    for (int u = 0; u < 4; ++u) o[u] = (v[u] - mu) * rs * g[u] + be[u];
    *(f32x4*)(out + (size_t)(i0 + r) * EMB + lane * 4) = o;
  }
}

extern "C" void kernel_launch(void* const* d_in, const int* in_sizes, int n_in,
                              void* d_out, int out_size, void* d_ws, size_t ws_size,
                              hipStream_t stream)
{
  (void)in_sizes; (void)n_in; (void)out_size; (void)ws_size;
  const float* x        = (const float*)d_in[0];
  const int*   adj      = (const int*)d_in[1];
  const float* W_lin    = (const float*)d_in[2];
  const float* att_src  = (const float*)d_in[3];
  const float* att_dst  = (const float*)d_in[4];
  const float* bias_att = (const float*)d_in[5];
  const float* W_out    = (const float*)d_in[6];
  const float* b_out    = (const float*)d_in[7];
  const float* gamma    = (const float*)d_in[8];
  const float* beta     = (const float*)d_in[9];
  float* out = (float*)d_out;

  uint8_t* p = (uint8_t*)d_ws;
  ushort_t* WlT = (ushort_t*)p;  p += (size_t)EMB * EMB * sizeof(ushort_t);
  ushort_t* WoT = (ushort_t*)p;  p += (size_t)EMB * EMB * sizeof(ushort_t);
  ushort_t* hT  = (ushort_t*)p;  p += (size_t)NH * HC * N * sizeof(ushort_t);
  float* a_srcb = (float*)p;     p += (size_t)NH * N * sizeof(float);
  float* a_dstb = (float*)p;     p += (size_t)NH * N * sizeof(float);
  ushort_t* oat = (ushort_t*)p;  p += (size_t)N * EMB * sizeof(ushort_t);

  k_transpose_bf<<<2 * EMB, EMB, 0, stream>>>(W_lin, WlT, W_out, WoT);
  k1_gemm_h<<<dim3(N / 64, NH), 256, 0, stream>>>(x, WlT, att_src, att_dst, hT, a_srcb, a_dstb);
  k34_attn<<<dim3(N / 16, 2), 512, 0, stream>>>(adj, hT, a_srcb, a_dstb, bias_att, oat);
  k5_gemm_ln<<<N / 16, 256, 0, stream>>>(oat, WoT, b_out, gamma, beta, out);
}

// Round 6
// 181.762 us; speedup vs baseline: 14.4399x; 1.1996x over previous
//
#include <hip/hip_runtime.h>
#include <stdint.h>

#define N    4096
#define EMB  256
#define NH   4
#define HC   64     // channels per head
#define PAD  40     // LDS inner stride (elements): 80B = 20 banks -> <=2-way

typedef __attribute__((ext_vector_type(8))) short s16x8;   // 8 bf16 frag
typedef __attribute__((ext_vector_type(4))) float f32x4;
typedef __attribute__((ext_vector_type(4))) int   i32x4;
typedef unsigned short ushort_t;

__device__ __forceinline__ unsigned short f2bf(float f) {
  unsigned int u = __builtin_bit_cast(unsigned int, f);
  u += 0x7fffu + ((u >> 16) & 1u);      // RNE (finite values only)
  return (unsigned short)(u >> 16);
}

// ---------------- K0: W[k][m] -> WT[m][k] as bf16 (both weights, one launch)
__global__ void k_transpose_bf(const float* __restrict__ W0, ushort_t* __restrict__ WT0,
                               const float* __restrict__ W1, ushort_t* __restrict__ WT1) {
  int k = blockIdx.x & 255;
  int m = threadIdx.x;
  if (blockIdx.x < 256) WT0[m * EMB + k] = f2bf(W0[k * EMB + m]);
  else                  WT1[m * EMB + k] = f2bf(W1[k * EMB + m]);
}

// ---------------- K2: pack adjacency to transposed bitmask -----------------
// abits[jw][i] (jw = j/32, 128 x 4096 uint32): bit b = (adj[i][jw*32+b] != 0),
// self-loop bit pre-OR'd. k34 lanes then read consecutive i -> coalesced 4B.
__global__ __launch_bounds__(256)
void k2_pack(const int* __restrict__ adj, unsigned int* __restrict__ abits) {
  int idx = blockIdx.x * 256 + threadIdx.x;
  int i = idx & (N - 1);
  int jw = idx >> 12;                    // 0..127
  const int* src = adj + (size_t)i * N + jw * 32;
  unsigned int word = 0;
  #pragma unroll
  for (int u = 0; u < 8; ++u) {
    i32x4 v = *(const i32x4*)(src + u * 4);
    #pragma unroll
    for (int b = 0; b < 4; ++b)
      word |= (v[b] != 0 ? 1u : 0u) << (u * 4 + b);
  }
  if ((i >> 5) == jw) word |= 1u << (i & 31);    // self-loop
  abits[(size_t)jw * N + i] = word;
}

// ---------------- K1: h = x @ W_lin (bf16 MFMA), epilogue:
//   hS[head][node/32][c][node%32] (bf16, MFMA-fragment tile order),
//   a_srcT[h][node], a_dstT[h][node] (fp32) ----------
__global__ __launch_bounds__(256, 2)
void k1_gemm_h(const float* __restrict__ x,
               const ushort_t* __restrict__ WlT,      // [256 m][256 k]
               const float* __restrict__ att_src,     // [4][64]
               const float* __restrict__ att_dst,
               ushort_t* __restrict__ hS,             // [4][128][64][32]
               float* __restrict__ a_srcT,            // [4][4096]
               float* __restrict__ a_dstT)
{
  __shared__ ushort_t A_lds[64][PAD];
  __shared__ ushort_t B_lds[64][PAD];
  __shared__ ushort_t T_lds[64][72];    // repack tile [c][node], 72: 16B-aligned rows
  const int t = threadIdx.x;
  const int lane = t & 63;
  const int w = t >> 6;
  const int i0 = blockIdx.x * 64;
  const int head = blockIdx.y;
  const int c0 = head * 64;
  const int lq = lane >> 4, lm = lane & 15;
  const int srow = t >> 2, sko = (t & 3) * 8;

  f32x4 acc[4];
  #pragma unroll
  for (int nf = 0; nf < 4; ++nf) acc[nf] = f32x4{0.f, 0.f, 0.f, 0.f};

  for (int k0 = 0; k0 < EMB; k0 += 32) {
    __syncthreads();
    {
      const float* src = x + (i0 + srow) * EMB + k0 + sko;
      f32x4 v0 = *(const f32x4*)src;
      f32x4 v1 = *(const f32x4*)(src + 4);
      s16x8 p;
      p[0]=(short)f2bf(v0[0]); p[1]=(short)f2bf(v0[1]); p[2]=(short)f2bf(v0[2]); p[3]=(short)f2bf(v0[3]);
      p[4]=(short)f2bf(v1[0]); p[5]=(short)f2bf(v1[1]); p[6]=(short)f2bf(v1[2]); p[7]=(short)f2bf(v1[3]);
      *(s16x8*)&A_lds[srow][sko] = p;
      *(s16x8*)&B_lds[srow][sko] = *(const s16x8*)(WlT + (c0 + srow) * EMB + k0 + sko);
    }
    __syncthreads();
    s16x8 a = *(const s16x8*)&A_lds[w * 16 + lm][lq * 8];
    #pragma unroll
    for (int nf = 0; nf < 4; ++nf) {
      s16x8 b = *(const s16x8*)&B_lds[nf * 16 + lm][lq * 8];
      acc[nf] = __builtin_amdgcn_mfma_f32_16x16x32_bf16(a, b, acc[nf], 0, 0, 0);
    }
  }

  float ps[4] = {0.f,0.f,0.f,0.f}, pd[4] = {0.f,0.f,0.f,0.f};
  #pragma unroll
  for (int nf = 0; nf < 4; ++nf) {
    float wsv = att_src[c0 + nf * 16 + lm];
    float wdv = att_dst[c0 + nf * 16 + lm];
    #pragma unroll
    for (int r = 0; r < 4; ++r) {
      float v = acc[nf][r];
      int node = w * 16 + lq * 4 + r;                 // D: row=(lane>>4)*4+reg, col=lane&15
      T_lds[nf * 16 + lm][node] = f2bf(v);            // park C^T tile in LDS
      ps[r] += v * wsv;
      pd[r] += v * wdv;
    }
  }
  #pragma unroll
  for (int r = 0; r < 4; ++r) {
    #pragma unroll
    for (int mm = 1; mm < 16; mm <<= 1) {
      ps[r] += __shfl_xor(ps[r], mm);
      pd[r] += __shfl_xor(pd[r], mm);
    }
  }
  if (lm == 0) {
    #pragma unroll
    for (int r = 0; r < 4; ++r) {
      int node = i0 + w * 16 + lq * 4 + r;
      a_srcT[head * N + node] = ps[r];
      a_dstT[head * N + node] = pd[r];
    }
  }
  __syncthreads();
  // hS store: thread t -> c = t>>2, seg = t&3 (16 local nodes each).
  // hS[head][jb][c][jj]: jb = i0/32 + (seg>>1), jj0 = (seg&1)*16.
  {
    int c = t >> 2, seg = t & 3;
    s16x8 v0 = *(const s16x8*)&T_lds[c][seg * 16];
    s16x8 v1 = *(const s16x8*)&T_lds[c][seg * 16 + 8];
    size_t base = (((size_t)head * 128 + (i0 >> 5) + (seg >> 1)) * 64 + c) * 32 + (seg & 1) * 16;
    *(s16x8*)(hS + base) = v0;
    *(s16x8*)(hS + base + 8) = v1;
  }
}

// ---------------- K34: fused masked-softmax attention, atomic-free ---------
// Block = 512 thr = 8 waves = (2 heads x 4 j-quarters); i-tile = 16 rows;
// grid = (N/16, 2 head-pairs) = 512 blocks -> 2 blocks/CU, 16 waves/CU.
// Memory paths (the R5 fix): B-frags from hS tiles = 1KB fully-coalesced
// loads; adjacency from abits bitmask = one broadcast 4B word per iter
// (R5 evidence: 8KB/16KB-strided frag loads -> ~64 L1 transactions each ->
// 108us TA-bound). e computed in MFMA A-frag layout (trunc-bf16; denominator
// sums the same truncated values). Static indexing only.
__global__ __launch_bounds__(512, 2)
void k34_attn(const unsigned int* __restrict__ abits, // [128 jw][4096 i]
              const ushort_t* __restrict__ hS,        // [4][128][64][32]
              const float* __restrict__ a_srcT,       // [4][4096]
              const float* __restrict__ a_dstT,       // [4][4096]
              const float* __restrict__ bias_att,     // [256]
              ushort_t* __restrict__ oat)             // [4096][256]
{
  __shared__ float acc_lds[2][3][16][65];  // jq=1..3 partials per local head
  __shared__ float l_lds[2][4][16];

  const int t = threadIdx.x;
  const int lane = t & 63;
  const int w = t >> 6;            // 0..7
  const int hloc = w & 1;          // local head (of the pair)
  const int jq = w >> 1;           // j-quarter 0..3
  const int head = blockIdx.y * 2 + hloc;
  const int i0 = blockIdx.x * 16;
  const int lm = lane & 15, lq = lane >> 4;
  const int ig = i0 + lm;          // this lane's A-row (i)

  const float* asrc_h = a_srcT + head * N;
  const ushort_t* hS_h = hS + (size_t)head * 128 * 64 * 32;
  const float ad = a_dstT[head * N + ig];

  f32x4 acc[4];
  #pragma unroll
  for (int nf = 0; nf < 4; ++nf) acc[nf] = f32x4{0.f, 0.f, 0.f, 0.f};
  float lp = 0.f;

  #pragma unroll 2
  for (int it = 0; it < 32; ++it) {
    const int jw = jq * 32 + it;               // j-window (32 j's)
    const int jl = jw * 32 + lq * 8;           // this lane's first j

    unsigned int word = abits[(size_t)jw * N + ig];      // coalesced/broadcast
    f32x4 as0 = *(const f32x4*)(asrc_h + jl);
    f32x4 as1 = *(const f32x4*)(asrc_h + jl + 4);

    const ushort_t* tile = hS_h + (size_t)jw * 2048;     // [64 c][32 j]
    s16x8 b0 = *(const s16x8*)(tile + ( 0 + lm) * 32 + lq * 8);
    s16x8 b1 = *(const s16x8*)(tile + (16 + lm) * 32 + lq * 8);
    s16x8 b2 = *(const s16x8*)(tile + (32 + lm) * 32 + lq * 8);
    s16x8 b3 = *(const s16x8*)(tile + (48 + lm) * 32 + lq * 8);

    unsigned int ebits[8];
    #pragma unroll
    for (int jj = 0; jj < 8; ++jj) {
      float asv = (jj < 4) ? as0[jj] : as1[jj - 4];
      float sc = asv + ad;
      sc = fmaxf(sc, 0.2f * sc);                         // leaky relu
      bool con = (word >> (lq * 8 + jj)) & 1u;           // adj + self-loop
      float e = con ? __expf(sc) : 0.f;
      unsigned int eb = __builtin_bit_cast(unsigned int, e) & 0xffff0000u; // trunc bf16
      ebits[jj] = eb;
      lp += __builtin_bit_cast(float, eb);               // sum the SAME rounded value
    }
    i32x4 pk;
    #pragma unroll
    for (int u = 0; u < 4; ++u)
      pk[u] = (int)__builtin_amdgcn_perm(ebits[2 * u + 1], ebits[2 * u], 0x07060302u);
    s16x8 af = __builtin_bit_cast(s16x8, pk);

    acc[0] = __builtin_amdgcn_mfma_f32_16x16x32_bf16(af, b0, acc[0], 0, 0, 0);
    acc[1] = __builtin_amdgcn_mfma_f32_16x16x32_bf16(af, b1, acc[1], 0, 0, 0);
    acc[2] = __builtin_amdgcn_mfma_f32_16x16x32_bf16(af, b2, acc[2], 0, 0, 0);
    acc[3] = __builtin_amdgcn_mfma_f32_16x16x32_bf16(af, b3, acc[3], 0, 0, 0);
  }

  // denominator: quarter-row sum for row lm
  lp += __shfl_xor(lp, 16);
  lp += __shfl_xor(lp, 32);
  if (lq == 0) l_lds[hloc][jq][lm] = lp;

  // jq=1..3 park accumulators in LDS (C layout: row=lq*4+r, col=lm)
  if (jq != 0) {
    #pragma unroll
    for (int nf = 0; nf < 4; ++nf)
      #pragma unroll
      for (int r = 0; r < 4; ++r)
        acc_lds[hloc][jq - 1][lq * 4 + r][nf * 16 + lm] = acc[nf][r];
  }
  __syncthreads();
  if (jq == 0) {
    float linv[4];
    #pragma unroll
    for (int r = 0; r < 4; ++r) {
      int row = lq * 4 + r;
      linv[r] = 1.f / (l_lds[hloc][0][row] + l_lds[hloc][1][row] +
                       l_lds[hloc][2][row] + l_lds[hloc][3][row]);
    }
    #pragma unroll
    for (int nf = 0; nf < 4; ++nf) {
      float bia = bias_att[head * 64 + nf * 16 + lm];
      #pragma unroll
      for (int r = 0; r < 4; ++r) {
        int row = lq * 4 + r;
        float v = acc[nf][r] + acc_lds[hloc][0][row][nf * 16 + lm]
                             + acc_lds[hloc][1][row][nf * 16 + lm]
                             + acc_lds[hloc][2][row][nf * 16 + lm];
        oat[(size_t)(i0 + row) * EMB + head * 64 + nf * 16 + lm] = f2bf(v * linv[r] + bia);
      }
    }
  }
}

// ---------------- K5: y = oat @ W_out + b_out, then LayerNorm -------------
__global__ __launch_bounds__(256, 2)
void k5_gemm_ln(const ushort_t* __restrict__ oat,    // [4096][256]
                const ushort_t* __restrict__ WoT,    // [256 m][256 k]
                const float* __restrict__ b_out,
                const float* __restrict__ gamma,
                const float* __restrict__ beta,
                float* __restrict__ out)
{
  __shared__ ushort_t A_lds[16][PAD];
  __shared__ ushort_t B_lds[256][PAD];
  __shared__ float y_lds[16][260];
  const int t = threadIdx.x, lane = t & 63, w = t >> 6;
  const int i0 = blockIdx.x * 16;
  const int lq = lane >> 4, lm = lane & 15;

  f32x4 acc[4];
  #pragma unroll
  for (int nf = 0; nf < 4; ++nf) acc[nf] = f32x4{0.f, 0.f, 0.f, 0.f};

  for (int k0 = 0; k0 < EMB; k0 += 32) {
    __syncthreads();
    if (t < 64) {
      int row = t >> 2, ko = (t & 3) * 8;
      *(s16x8*)&A_lds[row][ko] = *(const s16x8*)(oat + (size_t)(i0 + row) * EMB + k0 + ko);
    }
    {
      const ushort_t* src = WoT + t * EMB + k0;
      #pragma unroll
      for (int u = 0; u < 4; ++u) *(s16x8*)&B_lds[t][u * 8] = *(const s16x8*)(src + u * 8);
    }
    __syncthreads();
    s16x8 a = *(const s16x8*)&A_lds[lm][lq * 8];
    #pragma unroll
    for (int nf = 0; nf < 4; ++nf) {
      s16x8 b = *(const s16x8*)&B_lds[w * 64 + nf * 16 + lm][lq * 8];
      acc[nf] = __builtin_amdgcn_mfma_f32_16x16x32_bf16(a, b, acc[nf], 0, 0, 0);
    }
  }
  #pragma unroll
  for (int nf = 0; nf < 4; ++nf)
    #pragma unroll
    for (int r = 0; r < 4; ++r) {
      int row = lq * 4 + r;
      int col = w * 64 + nf * 16 + lm;
      y_lds[row][col] = acc[nf][r] + b_out[col];
    }
  __syncthreads();
  f32x4 g  = *(const f32x4*)(gamma + lane * 4);
  f32x4 be = *(const f32x4*)(beta + lane * 4);
  #pragma unroll
  for (int r = w * 4; r < w * 4 + 4; ++r) {
    f32x4 v = *(const f32x4*)&y_lds[r][lane * 4];
    float s1 = v[0] + v[1] + v[2] + v[3];
    float s2 = v[0]*v[0] + v[1]*v[1] + v[2]*v[2] + v[3]*v[3];
    #pragma unroll
    for (int mm = 1; mm < 64; mm <<= 1) { s1 += __shfl_xor(s1, mm); s2 += __shfl_xor(s2, mm); }
    float mu = s1 * (1.f / 256.f);
    float var = s2 * (1.f / 256.f) - mu * mu;
    float rs = rsqrtf(var + 1e-5f);
    f32x4 o;
    #pragma unroll
    for (int u = 0; u < 4; ++u) o[u] = (v[u] - mu) * rs * g[u] + be[u];
    *(f32x4*)(out + (size_t)(i0 + r) * EMB + lane * 4) = o;
  }
}

extern "C" void kernel_launch(void* const* d_in, const int* in_sizes, int n_in,
                              void* d_out, int out_size, void* d_ws, size_t ws_size,
                              hipStream_t stream)
{
  (void)in_sizes; (void)n_in; (void)out_size; (void)ws_size;
  const float* x        = (const float*)d_in[0];
  const int*   adj      = (const int*)d_in[1];
  const float* W_lin    = (const float*)d_in[2];
  const float* att_src  = (const float*)d_in[3];
  const float* att_dst  = (const float*)d_in[4];
  const float* bias_att = (const float*)d_in[5];
  const float* W_out    = (const float*)d_in[6];
  const float* b_out    = (const float*)d_in[7];
  const float* gamma    = (const float*)d_in[8];
  const float* beta     = (const float*)d_in[9];
  float* out = (float*)d_out;

  uint8_t* p = (uint8_t*)d_ws;
  ushort_t* WlT = (ushort_t*)p;  p += (size_t)EMB * EMB * sizeof(ushort_t);
  ushort_t* WoT = (ushort_t*)p;  p += (size_t)EMB * EMB * sizeof(ushort_t);
  ushort_t* hS  = (ushort_t*)p;  p += (size_t)NH * HC * N * sizeof(ushort_t);
  float* a_srcb = (float*)p;     p += (size_t)NH * N * sizeof(float);
  float* a_dstb = (float*)p;     p += (size_t)NH * N * sizeof(float);
  ushort_t* oat = (ushort_t*)p;  p += (size_t)N * EMB * sizeof(ushort_t);
  unsigned int* abits = (unsigned int*)p; p += (size_t)(N / 32) * N * sizeof(unsigned int);

  k_transpose_bf<<<2 * EMB, EMB, 0, stream>>>(W_lin, WlT, W_out, WoT);
  k2_pack<<<(N / 32) * N / 256, 256, 0, stream>>>(adj, abits);
  k1_gemm_h<<<dim3(N / 64, NH), 256, 0, stream>>>(x, WlT, att_src, att_dst, hS, a_srcb, a_dstb);
  k34_attn<<<dim3(N / 16, 2), 512, 0, stream>>>(abits, hS, a_srcb, a_dstb, bias_att, oat);
  k5_gemm_ln<<<N / 16, 256, 0, stream>>>(oat, WoT, b_out, gamma, beta, out);
}